// Round 2
// baseline (1300.951 us; speedup 1.0000x reference)
//
#include <hip/hip_runtime.h>
#include <stdint.h>

// ---------------------------------------------------------------------------
// SSL_34857954574989: dense SSM with spectral-norm-scaled K.
// w = S x  =>  w_{t+1} = K11n w_t + gamma*K12n u_t ;  y_t = K21n w_t + gamma*K22n u_t
// Pipeline: build_K -> fused-Lanczos(sigma) -> finalize -> conv_u ->
//           GEMM1 (Bu bf16, in d_out) -> chunked scan -> GEMM2 (y f32).
// ---------------------------------------------------------------------------

#define LM 40            // Lanczos steps
#define CHUNK 128        // scan chunk length
#define WARM 12          // scan warm-up steps (|lambda|~0.016 -> 1e-21)
#define LBLK 32          // lanczos grid blocks (all co-resident)

typedef float f32x4 __attribute__((ext_vector_type(4)));
typedef __bf16 bf16x8 __attribute__((ext_vector_type(8)));
typedef unsigned int u32;
typedef unsigned short u16;

static __device__ __forceinline__ u16 f2bf(float f){
  u32 u = __float_as_uint(f);
  u32 r = (u + 0x7fffu + ((u >> 16) & 1u)) >> 16;
  return (u16)r;
}

// ---------------------------------------------------------------- build K_raw
__global__ __launch_bounds__(256) void build_K(const float* rho_raw, const float* theta,
    const float* K12, const float* K21, const float* K22, float* K, float* KT){
  int idx = blockIdx.x * 256 + threadIdx.x;      // 0 .. 1024*1024-1
  int i = idx >> 10, j = idx & 1023;
  float v;
  if (i < 512){
    if (j < 512){
      v = 0.f;
      if ((i >> 1) == (j >> 1)){
        int p = i >> 1;
        float rho = (1.f / (1.f + expf(-rho_raw[p]))) * 0.999f;
        float c = cosf(theta[p]), s = sinf(theta[p]);
        v = ((i & 1) == 0) ? (((j & 1) == 0) ? rho * c : -rho * s)
                           : (((j & 1) == 0) ? rho * s :  rho * c);
      }
    } else v = K12[i * 512 + (j - 512)];
  } else {
    if (j < 512) v = K21[(i - 512) * 512 + j];
    else         v = K22[(i - 512) * 512 + (j - 512)];
  }
  K[idx] = v;
  KT[j * 1024 + i] = v;
}

// ------------------------------------------------------------------ init ws
__global__ __launch_bounds__(256) void init_scalars(double* alpha, double* beta2, int* bar){
  int t = threadIdx.x;
  if (t < 64) alpha[t] = 0.0;
  if (t < 68) beta2[t] = 0.0;
  if (t < 8)  bar[t] = 0;
}

// ------------------------------------------------- grid barrier (monotonic)
static __device__ __forceinline__ void gridbar(int* cnt, int nblk, int& myg){
  myg += nblk;
  __threadfence();        // release my stores (all threads/waves)
  __syncthreads();
  if (threadIdx.x == 0){
    atomicAdd(cnt, 1);
    while (atomicAdd(cnt, 0) < myg) __builtin_amdgcn_s_sleep(2);
  }
  __syncthreads();
  __threadfence();        // acquire: invalidate L1 before reading others' data
}

// -------------------------------------------- fused Lanczos on K^T K (1 launch)
__global__ __launch_bounds__(256) void lanczos_fused(const float* K, const float* KT,
    float* Va, float* Vb, float* Vc, float* Y,
    double* alpha, double* beta2, int* bar){
  __shared__ float vl[1024];
  __shared__ float red[4];
  int t = threadIdx.x, wave = t >> 6, lane = t & 63;
  int myg = 0;
  float* V[3] = {Va, Vb, Vc};
  // init v0 (rows blockIdx*32 .. +31 owned by this block)
  {
    float v = 0.f;
    if (t < 32){
      int i = blockIdx.x * 32 + t;
      v = sinf(0.613f * (float)i + 0.271f) + 0.3f * sinf(0.0247f * (float)i + 1.3f);
      Va[i] = v;
    }
    if (wave == 0){
      float sq = v * v;
      #pragma unroll
      for (int off = 32; off; off >>= 1) sq += __shfl_down(sq, off);
      if (t == 0) atomicAdd(&beta2[0], (double)sq);
    }
  }
  gridbar(bar, LBLK, myg);
  for (int j = 0; j < LM; ++j){
    const float* vraw  = V[j % 3];
    float*       vout  = V[(j + 1) % 3];
    const float* vprev = V[(j + 2) % 3];
    double b2 = beta2[j];
    float s = (b2 > 1e-280) ? (float)(1.0 / sqrt(b2)) : 0.f;
    for (int i = t; i < 1024; i += 256) vl[i] = vraw[i] * s;
    __syncthreads();
    // phase A: y = K v_hat, alpha_j = ||y||^2
    float sq = 0.f;
    #pragma unroll
    for (int rr = 0; rr < 8; ++rr){
      int row = blockIdx.x * 32 + wave * 8 + rr;
      const float* kr = K + (size_t)row * 1024;
      float p = 0.f;
      #pragma unroll
      for (int i2 = 0; i2 < 16; ++i2) p += kr[lane + 64 * i2] * vl[lane + 64 * i2];
      #pragma unroll
      for (int off = 32; off; off >>= 1) p += __shfl_down(p, off);
      if (lane == 0){ Y[row] = p; sq += p * p; }
    }
    if (lane == 0) red[wave] = sq;
    __syncthreads();
    if (t == 0) atomicAdd(&alpha[j], (double)(red[0] + red[1] + red[2] + red[3]));
    gridbar(bar, LBLK, myg);
    // phase B: w = K^T y - alpha v_hat - beta_{j-1} v_hat_{j-1}
    float alphaf = (float)alpha[j];
    float betap = (float)sqrt(b2 > 0.0 ? b2 : 0.0);
    float sp = 0.f;
    if (j > 0){
      double b2p = beta2[j - 1];
      sp = (b2p > 1e-280) ? (float)(1.0 / sqrt(b2p)) : 0.f;
    }
    for (int i = t; i < 1024; i += 256) vl[i] = Y[i];
    __syncthreads();
    sq = 0.f;
    #pragma unroll
    for (int rr = 0; rr < 8; ++rr){
      int row = blockIdx.x * 32 + wave * 8 + rr;
      const float* kr = KT + (size_t)row * 1024;
      float p = 0.f;
      #pragma unroll
      for (int i2 = 0; i2 < 16; ++i2) p += kr[lane + 64 * i2] * vl[lane + 64 * i2];
      #pragma unroll
      for (int off = 32; off; off >>= 1) p += __shfl_down(p, off);
      if (lane == 0){
        float wv = p - alphaf * (vraw[row] * s);
        if (j > 0) wv -= betap * (vprev[row] * sp);
        vout[row] = wv; sq += wv * wv;
      }
    }
    if (lane == 0) red[wave] = sq;
    __syncthreads();
    if (t == 0) atomicAdd(&beta2[j + 1], (double)(red[0] + red[1] + red[2] + red[3]));
    gridbar(bar, LBLK, myg);
  }
}

// ------------------------------------------------- finalize: sigma + scan coef
__global__ __launch_bounds__(256) void finalize_sigma(const double* alpha, const double* beta2,
    const float* rho_raw, const float* theta, const float* log_gamma,
    float* scal, float2* coef){
  __shared__ double sa[LM], sb2[LM + 1];
  __shared__ float sh_inv;
  int t = threadIdx.x;
  if (t < LM) sa[t] = alpha[t];
  if (t < LM + 1) sb2[t] = beta2[t];
  __syncthreads();
  if (t < 64){
    int lane = t;
    double lo = sa[0], hi = sa[0], bmax = 0.0;
    for (int i = 0; i < LM; ++i){
      if (sa[i] > lo) lo = sa[i];
      double bl = (i > 0) ? sqrt(fmax(sb2[i], 0.0)) : 0.0;
      double br = (i < LM - 1) ? sqrt(fmax(sb2[i + 1], 0.0)) : 0.0;
      double g = sa[i] + bl + br;
      if (g > hi) hi = g;
      if (i < LM - 1 && sb2[i + 1] > bmax) bmax = sb2[i + 1];
    }
    hi = hi + 1e-6 * fabs(hi) + 1e-20;
    lo = lo - 1e-6 * fabs(lo) - 1e-20;
    double pivmin = 1e-30 * bmax + 1e-300;
    for (int round = 0; round < 6; ++round){
      double x = lo + (hi - lo) * ((double)(lane + 1) / 65.0);
      double d = sa[0] - x; int cnt = (d < 0.0);
      for (int i = 1; i < LM; ++i){
        if (fabs(d) < pivmin) d = -pivmin;
        d = (sa[i] - x) - sb2[i] / d;
        cnt += (d < 0.0);
      }
      unsigned long long mk = __ballot(cnt >= LM);
      int bpos = (mk == 0ULL) ? 64 : (__ffsll((unsigned long long)mk) - 1);
      double xlo = __shfl(x, (bpos == 0) ? 0 : bpos - 1);
      double xhi = __shfl(x, (bpos == 64) ? 63 : bpos);
      double nlo = (bpos == 0) ? lo : xlo;
      double nhi = (bpos == 64) ? hi : xhi;
      lo = nlo; hi = nhi;
    }
    if (lane == 0){
      double lam = 0.5 * (lo + hi);
      double sig = (lam > 0.0) ? sqrt(lam) : 0.0;
      if (sig < 1e-5) sig = 1e-5;
      double spp = sig + 0.002;
      float inv = (float)(1.0 / spp);
      float g = expf(log_gamma[0]);
      scal[0] = inv; scal[1] = g; scal[2] = g * inv;
      sh_inv = inv;
    }
  }
  __syncthreads();
  float inv = sh_inv;
  float rho = (1.f / (1.f + expf(-rho_raw[t]))) * 0.999f;
  float c = cosf(theta[t]), s = sinf(theta[t]);
  coef[t] = make_float2(rho * c * inv, rho * s * inv);
}

// ------------------------------------------------------------- converts / prep
__global__ __launch_bounds__(256) void conv_u(const float4* u4, u16* X){
  long g = (long)blockIdx.x * 256 + threadIdx.x;     // 8388608 total
  float4 v = u4[g];
  int h4 = (int)(g & 127);
  long row = g >> 7;
  u16* dst = X + row * 1024 + 512 + h4 * 4;
  u32 lo = (u32)f2bf(v.x) | ((u32)f2bf(v.y) << 16);
  u32 hi = (u32)f2bf(v.z) | ((u32)f2bf(v.w) << 16);
  *((uint2*)dst) = make_uint2(lo, hi);
}

__global__ __launch_bounds__(256) void conv_w12(const float4* src, u16* dst){
  long g = (long)blockIdx.x * 256 + threadIdx.x;     // 65536 total
  float4 v = src[g];
  u32 lo = (u32)f2bf(v.x) | ((u32)f2bf(v.y) << 16);
  u32 hi = (u32)f2bf(v.z) | ((u32)f2bf(v.w) << 16);
  ((uint2*)dst)[g] = make_uint2(lo, hi);
}

__global__ __launch_bounds__(256) void build_wcat(const float* K21, const float* K22,
    const float* scal, u16* W){
  int idx = blockIdx.x * 256 + threadIdx.x;          // 524288 total
  int o = idx >> 10, c = idx & 1023;
  float inv = scal[0], gi = scal[2];
  float v = (c < 512) ? K21[o * 512 + c] * inv : K22[o * 512 + (c - 512)] * gi;
  W[idx] = f2bf(v);
}

// w0[b][n] = sum_m S[n][m] * state[b][m]
__global__ __launch_bounds__(256) void w0_matvec(const float* S, const float* state, float* w0){
  int idx = blockIdx.x * 256 + threadIdx.x;          // 8192 total
  int b = idx >> 9, n = idx & 511;
  const float* sr = S + n * 512;
  const float* st = state + b * 512;
  float acc = 0.f;
  for (int m2 = 0; m2 < 512; ++m2) acc += sr[m2] * st[m2];
  w0[idx] = acc;
}

// ------------------------------------------------------------------- the scan
// Bu is bf16 pairs packed in u32: [b][t][256]
__global__ __launch_bounds__(256) void scan_kernel(const u32* Bu, const float2* coef,
    const float* w0, const float* scal, u16* X){
  int b = blockIdx.x >> 5;           // 16 batches
  int c = blockIdx.x & 31;           // 32 chunks of 128
  int p = threadIdx.x;               // 256 pairs
  float2 ab = coef[p];
  float gi = scal[2];
  int t0 = c * CHUNK;
  float wx, wy; int t;
  if (c == 0){ wx = w0[b * 512 + 2 * p]; wy = w0[b * 512 + 2 * p + 1]; t = 0; }
  else { wx = 0.f; wy = 0.f; t = t0 - WARM; }
  const u32* bub = Bu + (size_t)b * 4096 * 256;
  u16* xb = X + (size_t)b * 4096 * 1024;
  for (; t < t0; ++t){
    u32 v = bub[(size_t)t * 256 + p];
    float bx = __uint_as_float(v << 16);
    float by = __uint_as_float(v & 0xffff0000u);
    float nx = ab.x * wx - ab.y * wy + gi * bx;
    float ny = ab.y * wx + ab.x * wy + gi * by;
    wx = nx; wy = ny;
  }
  for (; t < t0 + CHUNK; ++t){
    u32 pk = (u32)f2bf(wx) | ((u32)f2bf(wy) << 16);
    *(u32*)(xb + (size_t)t * 1024 + 2 * p) = pk;
    u32 v = bub[(size_t)t * 256 + p];
    float bx = __uint_as_float(v << 16);
    float by = __uint_as_float(v & 0xffff0000u);
    float nx = ab.x * wx - ab.y * wy + gi * bx;
    float ny = ab.y * wx + ab.x * wy + gi * by;
    wx = nx; wy = ny;
  }
}

// ------------------------------------------------------------------ bf16 GEMM
// C[M x N] = A[M x K] bf16 * B[N x K]^T bf16. 128x128 tile, BK=64.
// XCD-partitioned block swizzle; XOR-swizzled LDS layout (conflict-free BK=64).
static __device__ __forceinline__ void gload16(const u16* g, u16* l){
  __builtin_amdgcn_global_load_lds((const __attribute__((address_space(1))) u32*)g,
                                   (__attribute__((address_space(3))) u32*)l, 16, 0, 0);
}

template <typename OT>
__global__ __launch_bounds__(256) void gemm_nt(const u16* __restrict__ A, int lda,
    const u16* __restrict__ B, int ldb, OT* __restrict__ C, int ldc, int K){
  __shared__ u16 As[128 * 64];
  __shared__ u16 Bs[128 * 64];
  int g = blockIdx.x;
  int xcd = g & 7, local = g >> 3;
  int mperx = gridDim.x >> 5;                 // grid/8 xcds/4 ntiles
  int bm = xcd * mperx + (local >> 2);
  int bn = local & 3;
  int t = threadIdx.x, lane = t & 63, wave = t >> 6;
  int lrow = t >> 3;                          // 0..31
  int swz = (((t & 7) ^ (lrow & 7)) << 3);    // XOR-swizzled col offset (elems)
  const u16* Ag = A + (size_t)(bm * 128 + lrow) * lda + swz;
  const u16* Bg = B + (size_t)(bn * 128 + lrow) * ldb + swz;
  u16* Asd = As + t * 8;
  u16* Bsd = Bs + t * 8;
  f32x4 acc[4][4];
  #pragma unroll
  for (int mi = 0; mi < 4; ++mi)
    #pragma unroll
    for (int ni = 0; ni < 4; ++ni) acc[mi][ni] = (f32x4){0.f, 0.f, 0.f, 0.f};
  int wm = (wave & 1) << 6, wn = (wave >> 1) << 6;
  int fr = lane & 15, cbb = lane >> 4;
  for (int kt = 0; kt < K; kt += 64){
    __syncthreads();
    #pragma unroll
    for (int r = 0; r < 4; ++r){
      gload16(Ag + (size_t)(r * 32) * lda + kt, Asd + r * 2048);
      gload16(Bg + (size_t)(r * 32) * ldb + kt, Bsd + r * 2048);
    }
    __syncthreads();
    #pragma unroll
    for (int kk = 0; kk < 2; ++kk){
      bf16x8 af[4], bfr[4];
      #pragma unroll
      for (int mi = 0; mi < 4; ++mi){
        int row = wm + mi * 16 + fr;
        int pcb = ((kk << 2) + cbb) ^ (fr & 7);
        af[mi] = *(const bf16x8*)(As + row * 64 + pcb * 8);
      }
      #pragma unroll
      for (int ni = 0; ni < 4; ++ni){
        int row = wn + ni * 16 + fr;
        int pcb = ((kk << 2) + cbb) ^ (fr & 7);
        bfr[ni] = *(const bf16x8*)(Bs + row * 64 + pcb * 8);
      }
      #pragma unroll
      for (int mi = 0; mi < 4; ++mi)
        #pragma unroll
        for (int ni = 0; ni < 4; ++ni)
          acc[mi][ni] = __builtin_amdgcn_mfma_f32_16x16x32_bf16(af[mi], bfr[ni], acc[mi][ni], 0, 0, 0);
    }
  }
  int rq = lane >> 4;
  #pragma unroll
  for (int mi = 0; mi < 4; ++mi)
    #pragma unroll
    for (int ni = 0; ni < 4; ++ni){
      size_t base = (size_t)(bm * 128 + wm + mi * 16 + rq * 4) * ldc
                  + (size_t)(bn * 128 + wn + ni * 16 + fr);
      #pragma unroll
      for (int r = 0; r < 4; ++r){
        if constexpr (sizeof(OT) == 4) C[base + (size_t)r * ldc] = acc[mi][ni][r];
        else                           C[base + (size_t)r * ldc] = (OT)f2bf(acc[mi][ni][r]);
      }
    }
}

// ------------------------------------------------------------------- launcher
extern "C" void kernel_launch(void* const* d_in, const int* in_sizes, int n_in,
                              void* d_out, int out_size, void* d_ws, size_t ws_size,
                              hipStream_t stream){
  const float* u        = (const float*)d_in[0];
  const float* state    = (const float*)d_in[1];
  const float* S        = (const float*)d_in[2];
  const float* rho_raw  = (const float*)d_in[3];
  const float* theta    = (const float*)d_in[4];
  const float* K12      = (const float*)d_in[5];
  const float* K21      = (const float*)d_in[6];
  const float* K22      = (const float*)d_in[7];
  const float* log_gamma= (const float*)d_in[8];

  char* w = (char*)d_ws;
  size_t off = 0;
  auto alloc = [&](size_t bytes)->void*{
    void* p = w + off;
    off = (off + bytes + 255) & ~(size_t)255;
    return p;
  };
  double* alpha = (double*)alloc(64 * 8);
  double* beta2 = (double*)alloc(68 * 8);
  int*    bar   = (int*)alloc(64);
  float*  scal  = (float*)alloc(64);
  float2* coef  = (float2*)alloc(256 * 8);
  float*  V0    = (float*)alloc(1024 * 4);
  float*  V1    = (float*)alloc(1024 * 4);
  float*  V2    = (float*)alloc(1024 * 4);
  float*  Y     = (float*)alloc(1024 * 4);
  float*  w0    = (float*)alloc(16 * 512 * 4);
  float*  Kd    = (float*)alloc((size_t)1024 * 1024 * 4);
  float*  KTd   = (float*)alloc((size_t)1024 * 1024 * 4);
  u16*    W12   = (u16*)alloc((size_t)512 * 512 * 2);
  u16*    Wcat  = (u16*)alloc((size_t)512 * 1024 * 2);
  u16*    Xb    = (u16*)alloc((size_t)65536 * 1024 * 2);
  // Bu (bf16, 67 MB) aliases d_out; consumed by scan before GEMM2 overwrites.
  u16*    Bu    = (u16*)d_out;

  init_scalars<<<1, 256, 0, stream>>>(alpha, beta2, bar);
  build_K<<<4096, 256, 0, stream>>>(rho_raw, theta, K12, K21, K22, Kd, KTd);
  lanczos_fused<<<LBLK, 256, 0, stream>>>(Kd, KTd, V0, V1, V2, Y, alpha, beta2, bar);
  finalize_sigma<<<1, 256, 0, stream>>>(alpha, beta2, rho_raw, theta, log_gamma, scal, coef);

  conv_u<<<32768, 256, 0, stream>>>((const float4*)u, Xb);
  conv_w12<<<256, 256, 0, stream>>>((const float4*)K12, W12);
  build_wcat<<<2048, 256, 0, stream>>>(K21, K22, scal, Wcat);
  w0_matvec<<<32, 256, 0, stream>>>(S, state, w0);

  // GEMM1: Bu(bf16) = u_bf16 @ K12^T   (M=65536, N=512, K=512)
  gemm_nt<u16><<<2048, 256, 0, stream>>>(Xb + 512, 1024, W12, 512, Bu, 512, 512);
  // scan: pre (bf16) into X[:, 0:512]
  scan_kernel<<<512, 256, 0, stream>>>((const u32*)Bu, coef, w0, scal, Xb);
  // GEMM2: y = [pre|u] @ [K21n | gamma*K22n]^T  (M=65536, N=512, K=1024)
  gemm_nt<float><<<2048, 256, 0, stream>>>(Xb, 1024, Wcat, 1024, (float*)d_out, 512, 1024);
}

// Round 3
// 783.062 us; speedup vs baseline: 1.6614x; 1.6614x over previous
//
#include <hip/hip_runtime.h>
#include <stdint.h>

// ---------------------------------------------------------------------------
// SSL_34857954574989: dense SSM with spectral-norm-scaled K.
// w = S x  =>  w_{t+1} = K11n w_t + gamma*K12n u_t ;  y_t = K21n w_t + gamma*K22n u_t
// sigma path: KT(bf16) -> G = K^T K (MFMA GEMM, f32 out) -> 40-step Lanczos on G
// in ONE persistent kernel (32 blocks) with fence-free relaxed-atomic barriers
// (2 per iter) -> Sturm bisection.
// Main path: conv_u -> GEMM1 (Bu bf16, in d_out) -> chunked scan -> GEMM2.
// ---------------------------------------------------------------------------

#define LM 40            // Lanczos steps
#define CHUNK 128        // scan chunk length
#define WARM 12          // scan warm-up steps
#define LBLK 32          // lanczos grid blocks (all co-resident; 32 rows each)

typedef float f32x4 __attribute__((ext_vector_type(4)));
typedef __bf16 bf16x8 __attribute__((ext_vector_type(8)));
typedef unsigned int u32;
typedef unsigned short u16;

static __device__ __forceinline__ u16 f2bf(float f){
  u32 u = __float_as_uint(f);
  u32 r = (u + 0x7fffu + ((u >> 16) & 1u)) >> 16;
  return (u16)r;
}

// K_raw(i,j) evaluated directly (i=row, j=col of the 1024x1024 block matrix)
static __device__ __forceinline__ float kraw_at(int i, int j,
    const float* rho_raw, const float* theta,
    const float* K12, const float* K21, const float* K22){
  if (i < 512){
    if (j < 512){
      if ((i >> 1) != (j >> 1)) return 0.f;
      int p = i >> 1;
      float rho = (1.f / (1.f + expf(-rho_raw[p]))) * 0.999f;
      float c = cosf(theta[p]), s = sinf(theta[p]);
      return ((i & 1) == 0) ? (((j & 1) == 0) ? rho * c : -rho * s)
                            : (((j & 1) == 0) ? rho * s :  rho * c);
    }
    return K12[i * 512 + (j - 512)];
  }
  if (j < 512) return K21[(i - 512) * 512 + j];
  return K22[(i - 512) * 512 + (j - 512)];
}

// KTbf[j][i] = bf16(K_raw(i,j)); thread owns output element (coalesced store)
__global__ __launch_bounds__(256) void build_KT(const float* rho_raw, const float* theta,
    const float* K12, const float* K21, const float* K22, u16* KTbf){
  int idx = blockIdx.x * 256 + threadIdx.x;      // 0 .. 1024*1024-1 (output idx)
  int j = idx >> 10, i = idx & 1023;             // KT row j, col i
  KTbf[idx] = f2bf(kraw_at(i, j, rho_raw, theta, K12, K21, K22));
}

// ------------------------------------------------------------------ init ws
__global__ __launch_bounds__(256) void init_scalars(double* alpha, double* nrm2, u32* flags){
  int t = threadIdx.x;
  if (t < 64) alpha[t] = 0.0;
  if (t < 64) nrm2[t] = 0.0;
  if (t < 128) flags[t] = 0u;
}

// --------------------------------------------- fence-free barrier primitives
static __device__ __forceinline__ void bar_arrive(u32* flag){
  asm volatile("s_waitcnt vmcnt(0)" ::: "memory");   // per-wave: drain my stores/atomics
  __syncthreads();                                   // all waves drained
  if (threadIdx.x == 0)
    __hip_atomic_fetch_add(flag, 1u, __ATOMIC_RELAXED, __HIP_MEMORY_SCOPE_AGENT);
}
static __device__ __forceinline__ void bar_wait(u32* flag){
  if (threadIdx.x == 0){
    while (__hip_atomic_load(flag, __ATOMIC_RELAXED, __HIP_MEMORY_SCOPE_AGENT) < (u32)LBLK)
      __builtin_amdgcn_s_sleep(2);
  }
  __syncthreads();
}

// ------------------------------------- Lanczos on G = K^T K (single launch)
// Block b owns rows [32b, 32b+32). Cross-block vector traffic via relaxed
// agent-scope atomics (write-through to coherence point; no bulk cache ops).
__global__ __launch_bounds__(256) void lanczos_G(const float* __restrict__ G,
    float* W0, float* W1, double* alpha, double* nrm2, u32* flags){
  __shared__ float vl[1024];      // current raw w_{j-1} (full vector)
  __shared__ float yloc[32];      // my rows of y = G vhat
  __shared__ float vprev[32];     // my rows of vhat_{j-1}
  __shared__ float red[4];
  __shared__ double shdbl;
  int t = threadIdx.x, wave = t >> 6, lane = t & 63;
  int row0 = blockIdx.x * 32;
  float* wbuf[2] = {W0, W1};

  // ---- v0 raw + deterministic redundant norm (identical in every block)
  for (int i = t; i < 1024; i += 256){
    float v = sinf(0.613f * (float)i + 0.271f) + 0.3f * sinf(0.0247f * (float)i + 1.3f);
    vl[i] = v;
  }
  __syncthreads();
  {
    float s = 0.f;
    for (int i = t; i < 1024; i += 256){ float v = vl[i]; s += v * v; }
    #pragma unroll
    for (int off = 32; off; off >>= 1) s += __shfl_down(s, off);
    if (lane == 0) red[wave] = s;
    __syncthreads();
    if (t == 0) shdbl = (double)((red[0] + red[1]) + (red[2] + red[3]));
    __syncthreads();
  }
  float scal = (float)(1.0 / sqrt(shdbl));    // 1/beta_0
  float betacoef = 0.f;                       // no v_prev term at j=1

  for (int j = 1; j <= LM; ++j){
    // ---- pass A: y(my rows) = G * vhat ; alpha_j = vhat^T y (atomic f64)
    float asum = 0.f;
    #pragma unroll
    for (int rr = 0; rr < 8; ++rr){
      int row = row0 + wave * 8 + rr;
      const float* gr = G + (size_t)row * 1024;
      float p = 0.f;
      #pragma unroll
      for (int i2 = 0; i2 < 16; ++i2) p += gr[lane + 64 * i2] * vl[lane + 64 * i2];
      #pragma unroll
      for (int off = 32; off; off >>= 1) p += __shfl_down(p, off);
      if (lane == 0){
        float y = p * scal;
        yloc[wave * 8 + rr] = y;
        asum += y * (vl[row] * scal);
      }
    }
    if (lane == 0) red[wave] = asum;
    __syncthreads();
    if (t == 0) atomicAdd(&alpha[j], (double)((red[0] + red[1]) + (red[2] + red[3])));
    bar_arrive(&flags[2 * j]);
    bar_wait(&flags[2 * j]);
    if (t == 0) shdbl = __hip_atomic_load(&alpha[j], __ATOMIC_RELAXED, __HIP_MEMORY_SCOPE_AGENT);
    __syncthreads();
    float af = (float)shdbl;
    // ---- pass B: w_j(my rows) = y - alpha*vhat - beta_{j-1}*vhat_prev
    float* Wt = wbuf[j & 1];
    if (t < 32){
      float vh = vl[row0 + t] * scal;
      float wv = yloc[t] - af * vh - betacoef * vprev[t];
      vprev[t] = vh;
      __hip_atomic_store(&Wt[row0 + t], wv, __ATOMIC_RELAXED, __HIP_MEMORY_SCOPE_AGENT);
      float sq = wv * wv;
      #pragma unroll
      for (int off = 16; off; off >>= 1) sq += __shfl_down(sq, off);
      if (t == 0) atomicAdd(&nrm2[j], (double)sq);
    }
    bar_arrive(&flags[2 * j + 1]);
    bar_wait(&flags[2 * j + 1]);
    if (j < LM){
      for (int i = t; i < 1024; i += 256)
        vl[i] = __hip_atomic_load(&Wt[i], __ATOMIC_RELAXED, __HIP_MEMORY_SCOPE_AGENT);
      if (t == 0) shdbl = __hip_atomic_load(&nrm2[j], __ATOMIC_RELAXED, __HIP_MEMORY_SCOPE_AGENT);
      __syncthreads();
      double b2 = shdbl;
      if (b2 < 1e-280) b2 = 1e-280;
      scal = (float)(1.0 / sqrt(b2));
      betacoef = (float)sqrt(b2);
    }
  }
}

// ------------------------------------------------- finalize: sigma + scan coef
// sa[0..LM-1] = alpha_1..alpha_LM ; sb2[i] = beta_i^2 (offdiag between i-1,i)
__global__ __launch_bounds__(256) void finalize_sigma(const double* alpha, const double* beta2,
    const float* rho_raw, const float* theta, const float* log_gamma,
    float* scal, float2* coef){
  __shared__ double sa[LM], sb2[LM + 1];
  __shared__ float sh_inv;
  int t = threadIdx.x;
  if (t < LM) sa[t] = alpha[t];
  if (t < LM + 1) sb2[t] = beta2[t];
  __syncthreads();
  if (t < 64){
    int lane = t;
    double lo = sa[0], hi = sa[0], bmax = 0.0;
    for (int i = 0; i < LM; ++i){
      if (sa[i] > lo) lo = sa[i];
      double bl = (i > 0) ? sqrt(fmax(sb2[i], 0.0)) : 0.0;
      double br = (i < LM - 1) ? sqrt(fmax(sb2[i + 1], 0.0)) : 0.0;
      double g = sa[i] + bl + br;
      if (g > hi) hi = g;
      if (i < LM - 1 && sb2[i + 1] > bmax) bmax = sb2[i + 1];
    }
    hi = hi + 1e-6 * fabs(hi) + 1e-20;
    lo = lo - 1e-6 * fabs(lo) - 1e-20;
    double pivmin = 1e-30 * bmax + 1e-300;
    for (int round = 0; round < 6; ++round){
      double x = lo + (hi - lo) * ((double)(lane + 1) / 65.0);
      double d = sa[0] - x; int cnt = (d < 0.0);
      for (int i = 1; i < LM; ++i){
        if (fabs(d) < pivmin) d = -pivmin;
        d = (sa[i] - x) - sb2[i] / d;
        cnt += (d < 0.0);
      }
      unsigned long long mk = __ballot(cnt >= LM);
      int bpos = (mk == 0ULL) ? 64 : (__ffsll((unsigned long long)mk) - 1);
      double xlo = __shfl(x, (bpos == 0) ? 0 : bpos - 1);
      double xhi = __shfl(x, (bpos == 64) ? 63 : bpos);
      double nlo = (bpos == 0) ? lo : xlo;
      double nhi = (bpos == 64) ? hi : xhi;
      lo = nlo; hi = nhi;
    }
    if (lane == 0){
      double lam = 0.5 * (lo + hi);
      double sig = (lam > 0.0) ? sqrt(lam) : 0.0;
      if (sig < 1e-5) sig = 1e-5;
      double spp = sig + 0.002;
      float inv = (float)(1.0 / spp);
      float g = expf(log_gamma[0]);
      scal[0] = inv; scal[1] = g; scal[2] = g * inv;
      sh_inv = inv;
    }
  }
  __syncthreads();
  float inv = sh_inv;
  float rho = (1.f / (1.f + expf(-rho_raw[t]))) * 0.999f;
  float c = cosf(theta[t]), s = sinf(theta[t]);
  coef[t] = make_float2(rho * c * inv, rho * s * inv);
}

// ------------------------------------------------------------- converts / prep
__global__ __launch_bounds__(256) void conv_u(const float4* u4, u16* X){
  long g = (long)blockIdx.x * 256 + threadIdx.x;     // 8388608 total
  float4 v = u4[g];
  int h4 = (int)(g & 127);
  long row = g >> 7;
  u16* dst = X + row * 1024 + 512 + h4 * 4;
  u32 lo = (u32)f2bf(v.x) | ((u32)f2bf(v.y) << 16);
  u32 hi = (u32)f2bf(v.z) | ((u32)f2bf(v.w) << 16);
  *((uint2*)dst) = make_uint2(lo, hi);
}

__global__ __launch_bounds__(256) void conv_w12(const float4* src, u16* dst){
  long g = (long)blockIdx.x * 256 + threadIdx.x;     // 65536 total
  float4 v = src[g];
  u32 lo = (u32)f2bf(v.x) | ((u32)f2bf(v.y) << 16);
  u32 hi = (u32)f2bf(v.z) | ((u32)f2bf(v.w) << 16);
  ((uint2*)dst)[g] = make_uint2(lo, hi);
}

__global__ __launch_bounds__(256) void build_wcat(const float* K21, const float* K22,
    const float* scal, u16* W){
  int idx = blockIdx.x * 256 + threadIdx.x;          // 524288 total
  int o = idx >> 10, c = idx & 1023;
  float inv = scal[0], gi = scal[2];
  float v = (c < 512) ? K21[o * 512 + c] * inv : K22[o * 512 + (c - 512)] * gi;
  W[idx] = f2bf(v);
}

// w0[b][n] = sum_m S[n][m] * state[b][m]
__global__ __launch_bounds__(256) void w0_matvec(const float* S, const float* state, float* w0){
  int idx = blockIdx.x * 256 + threadIdx.x;          // 8192 total
  int b = idx >> 9, n = idx & 511;
  const float* sr = S + n * 512;
  const float* st = state + b * 512;
  float acc = 0.f;
  for (int m2 = 0; m2 < 512; ++m2) acc += sr[m2] * st[m2];
  w0[idx] = acc;
}

// ------------------------------------------------------------------- the scan
// Bu is bf16 pairs packed in u32: [b][t][256]
__global__ __launch_bounds__(256) void scan_kernel(const u32* Bu, const float2* coef,
    const float* w0, const float* scal, u16* X){
  int b = blockIdx.x >> 5;           // 16 batches
  int c = blockIdx.x & 31;           // 32 chunks of 128
  int p = threadIdx.x;               // 256 pairs
  float2 ab = coef[p];
  float gi = scal[2];
  int t0 = c * CHUNK;
  float wx, wy; int t;
  if (c == 0){ wx = w0[b * 512 + 2 * p]; wy = w0[b * 512 + 2 * p + 1]; t = 0; }
  else { wx = 0.f; wy = 0.f; t = t0 - WARM; }
  const u32* bub = Bu + (size_t)b * 4096 * 256;
  u16* xb = X + (size_t)b * 4096 * 1024;
  for (; t < t0; ++t){
    u32 v = bub[(size_t)t * 256 + p];
    float bx = __uint_as_float(v << 16);
    float by = __uint_as_float(v & 0xffff0000u);
    float nx = ab.x * wx - ab.y * wy + gi * bx;
    float ny = ab.y * wx + ab.x * wy + gi * by;
    wx = nx; wy = ny;
  }
  for (; t < t0 + CHUNK; ++t){
    u32 pk = (u32)f2bf(wx) | ((u32)f2bf(wy) << 16);
    *(u32*)(xb + (size_t)t * 1024 + 2 * p) = pk;
    u32 v = bub[(size_t)t * 256 + p];
    float bx = __uint_as_float(v << 16);
    float by = __uint_as_float(v & 0xffff0000u);
    float nx = ab.x * wx - ab.y * wy + gi * bx;
    float ny = ab.y * wx + ab.x * wy + gi * by;
    wx = nx; wy = ny;
  }
}

// ------------------------------------------------------------------ bf16 GEMM
// C[M x N] = A[M x K] bf16 * B[N x K]^T bf16. 128x128 tile, BK=64.
// XCD-partitioned block swizzle; XOR-swizzled LDS layout.
static __device__ __forceinline__ void gload16(const u16* g, u16* l){
  __builtin_amdgcn_global_load_lds((const __attribute__((address_space(1))) u32*)g,
                                   (__attribute__((address_space(3))) u32*)l, 16, 0, 0);
}

template <typename OT>
__global__ __launch_bounds__(256) void gemm_nt(const u16* __restrict__ A, int lda,
    const u16* __restrict__ B, int ldb, OT* __restrict__ C, int ldc, int K, int ntn){
  __shared__ u16 As[128 * 64];
  __shared__ u16 Bs[128 * 64];
  int g = blockIdx.x;
  int xcd = g & 7, local = g >> 3;
  int mper = gridDim.x >> 3; mper /= ntn;     // m-tiles per xcd
  int bn = local % ntn;
  int bm = xcd * mper + local / ntn;
  int t = threadIdx.x, lane = t & 63, wave = t >> 6;
  int lrow = t >> 3;                          // 0..31
  int swz = (((t & 7) ^ (lrow & 7)) << 3);    // XOR-swizzled col offset (elems)
  const u16* Ag = A + (size_t)(bm * 128 + lrow) * lda + swz;
  const u16* Bg = B + (size_t)(bn * 128 + lrow) * ldb + swz;
  u16* Asd = As + t * 8;
  u16* Bsd = Bs + t * 8;
  f32x4 acc[4][4];
  #pragma unroll
  for (int mi = 0; mi < 4; ++mi)
    #pragma unroll
    for (int ni = 0; ni < 4; ++ni) acc[mi][ni] = (f32x4){0.f, 0.f, 0.f, 0.f};
  int wm = (wave & 1) << 6, wn = (wave >> 1) << 6;
  int fr = lane & 15, cbb = lane >> 4;
  for (int kt = 0; kt < K; kt += 64){
    __syncthreads();
    #pragma unroll
    for (int r = 0; r < 4; ++r){
      gload16(Ag + (size_t)(r * 32) * lda + kt, Asd + r * 2048);
      gload16(Bg + (size_t)(r * 32) * ldb + kt, Bsd + r * 2048);
    }
    __syncthreads();
    #pragma unroll
    for (int kk = 0; kk < 2; ++kk){
      bf16x8 af[4], bfr[4];
      #pragma unroll
      for (int mi = 0; mi < 4; ++mi){
        int row = wm + mi * 16 + fr;
        int pcb = ((kk << 2) + cbb) ^ (fr & 7);
        af[mi] = *(const bf16x8*)(As + row * 64 + pcb * 8);
      }
      #pragma unroll
      for (int ni = 0; ni < 4; ++ni){
        int row = wn + ni * 16 + fr;
        int pcb = ((kk << 2) + cbb) ^ (fr & 7);
        bfr[ni] = *(const bf16x8*)(Bs + row * 64 + pcb * 8);
      }
      #pragma unroll
      for (int mi = 0; mi < 4; ++mi)
        #pragma unroll
        for (int ni = 0; ni < 4; ++ni)
          acc[mi][ni] = __builtin_amdgcn_mfma_f32_16x16x32_bf16(af[mi], bfr[ni], acc[mi][ni], 0, 0, 0);
    }
  }
  int rq = lane >> 4;
  #pragma unroll
  for (int mi = 0; mi < 4; ++mi)
    #pragma unroll
    for (int ni = 0; ni < 4; ++ni){
      size_t base = (size_t)(bm * 128 + wm + mi * 16 + rq * 4) * ldc
                  + (size_t)(bn * 128 + wn + ni * 16 + fr);
      #pragma unroll
      for (int r = 0; r < 4; ++r){
        if constexpr (sizeof(OT) == 4) C[base + (size_t)r * ldc] = acc[mi][ni][r];
        else                           C[base + (size_t)r * ldc] = (OT)f2bf(acc[mi][ni][r]);
      }
    }
}

// ------------------------------------------------------------------- launcher
extern "C" void kernel_launch(void* const* d_in, const int* in_sizes, int n_in,
                              void* d_out, int out_size, void* d_ws, size_t ws_size,
                              hipStream_t stream){
  const float* u        = (const float*)d_in[0];
  const float* state    = (const float*)d_in[1];
  const float* S        = (const float*)d_in[2];
  const float* rho_raw  = (const float*)d_in[3];
  const float* theta    = (const float*)d_in[4];
  const float* K12      = (const float*)d_in[5];
  const float* K21      = (const float*)d_in[6];
  const float* K22      = (const float*)d_in[7];
  const float* log_gamma= (const float*)d_in[8];

  char* w = (char*)d_ws;
  size_t off = 0;
  auto alloc = [&](size_t bytes)->void*{
    void* p = w + off;
    off = (off + bytes + 255) & ~(size_t)255;
    return p;
  };
  double* alpha = (double*)alloc(64 * 8);
  double* nrm2  = (double*)alloc(64 * 8);
  u32*    flags = (u32*)alloc(128 * 4);
  float*  scal  = (float*)alloc(64);
  float2* coef  = (float2*)alloc(256 * 8);
  float*  W0    = (float*)alloc(1024 * 4);
  float*  W1    = (float*)alloc(1024 * 4);
  float*  w0    = (float*)alloc(16 * 512 * 4);
  u16*    KTbf  = (u16*)alloc((size_t)1024 * 1024 * 2);
  float*  G     = (float*)alloc((size_t)1024 * 1024 * 4);
  u16*    W12   = (u16*)alloc((size_t)512 * 512 * 2);
  u16*    Wcat  = (u16*)alloc((size_t)512 * 1024 * 2);
  u16*    Xb    = (u16*)alloc((size_t)65536 * 1024 * 2);
  // Bu (bf16, 67 MB) aliases d_out; consumed by scan before GEMM2 overwrites.
  u16*    Bu    = (u16*)d_out;

  init_scalars<<<1, 256, 0, stream>>>(alpha, nrm2, flags);
  build_KT<<<4096, 256, 0, stream>>>(rho_raw, theta, K12, K21, K22, KTbf);
  // G = K^T K = KT @ KT^T  (M=N=K=1024, f32 out)
  gemm_nt<float><<<64, 256, 0, stream>>>(KTbf, 1024, KTbf, 1024, G, 1024, 1024, 8);
  lanczos_G<<<LBLK, 256, 0, stream>>>(G, W0, W1, alpha, nrm2, flags);
  finalize_sigma<<<1, 256, 0, stream>>>(alpha + 1, nrm2, rho_raw, theta, log_gamma, scal, coef);

  conv_u<<<32768, 256, 0, stream>>>((const float4*)u, Xb);
  conv_w12<<<256, 256, 0, stream>>>((const float4*)K12, W12);
  build_wcat<<<2048, 256, 0, stream>>>(K21, K22, scal, Wcat);
  w0_matvec<<<32, 256, 0, stream>>>(S, state, w0);

  // GEMM1: Bu(bf16) = u_bf16 @ K12^T   (M=65536, N=512, K=512)
  gemm_nt<u16><<<2048, 256, 0, stream>>>(Xb + 512, 1024, W12, 512, Bu, 512, 512, 4);
  // scan: pre (bf16) into X[:, 0:512]
  scan_kernel<<<512, 256, 0, stream>>>((const u32*)Bu, coef, w0, scal, Xb);
  // GEMM2: y = [pre|u] @ [K21n | gamma*K22n]^T  (M=65536, N=512, K=1024)
  gemm_nt<float><<<2048, 256, 0, stream>>>(Xb, 1024, Wcat, 1024, (float*)d_out, 512, 1024, 4);
}